// Round 1
// baseline (6428.578 us; speedup 1.0000x reference)
//
#include <hip/hip_runtime.h>
#include <math.h>

#define TAN30f 0.57735026918962576f
#define SELU_SCALE 1.0507009873554805f
#define SELU_ALPHA 1.6732632423543772f

__device__ __forceinline__ float selu_f(float x) {
    return SELU_SCALE * (x > 0.0f ? x : SELU_ALPHA * expm1f(x));
}

// ---------- dense matmul: Y[N,128] = concat(X[N,FIC], P[N,3]?) @ W ----------
template<int FIC, bool HAS_POS, bool BIAS_SELU>
__global__ __launch_bounds__(256) void k_matmul128(
    const float* __restrict__ X, const float* __restrict__ P,
    const float* __restrict__ W, const float* __restrict__ bias,
    float* __restrict__ Y, int N)
{
    constexpr int ICT = FIC + (HAS_POS ? 3 : 0);
    __shared__ float xs[16][ICT + 1];
    int row0 = blockIdx.x * 16;

    for (int idx = threadIdx.x; idx < 16 * FIC; idx += 256) {
        int r = idx / FIC, c = idx % FIC;
        int gr = row0 + r;
        xs[r][c] = (gr < N) ? X[gr * FIC + c] : 0.0f;
    }
    if (HAS_POS) {
        for (int idx = threadIdx.x; idx < 16 * 3; idx += 256) {
            int r = idx / 3, c = idx % 3;
            int gr = row0 + r;
            xs[r][FIC + c] = (gr < N) ? P[gr * 3 + c] : 0.0f;
        }
    }
    __syncthreads();

    int col = threadIdx.x & 127;
    int half = threadIdx.x >> 7;
    float acc[8];
#pragma unroll
    for (int r = 0; r < 8; ++r) acc[r] = 0.0f;

#pragma unroll 4
    for (int i = 0; i < ICT; ++i) {
        float wv = W[i * 128 + col];
#pragma unroll
        for (int r = 0; r < 8; ++r)
            acc[r] = fmaf(xs[half * 8 + r][i], wv, acc[r]);
    }

    float bv = BIAS_SELU ? bias[col] : 0.0f;
#pragma unroll
    for (int r = 0; r < 8; ++r) {
        int gr = row0 + half * 8 + r;
        if (gr < N) {
            float v = acc[r];
            if (BIAS_SELU) v = selu_f(v + bv);
            Y[gr * 128 + col] = v;
        }
    }
}

// ---------- small helpers ----------
__global__ void k_fill(float* __restrict__ p, float v, int n) {
    int i = blockIdx.x * 256 + threadIdx.x;
    if (i < n) p[i] = v;
}

__global__ void k_count(const int* __restrict__ col, int E, float* __restrict__ deg) {
    int i = blockIdx.x * 256 + threadIdx.x;
    if (i < E) atomicAdd(&deg[col[i]], 1.0f);
}

__global__ void k_rsqrt(float* __restrict__ p, int n) {
    int i = blockIdx.x * 256 + threadIdx.x;
    if (i < n) p[i] = rsqrtf(p[i]);
}

__global__ void k_selfinit(const float* __restrict__ xw, const float* __restrict__ dinv,
                           float* __restrict__ out, int N) {
    int i = blockIdx.x * 256 + threadIdx.x;
    if (i < N * 128) {
        int r = i >> 7;
        float di = dinv[r];
        out[i] = xw[i] * di * di;
    }
}

__global__ void k_edge128(const int* __restrict__ rows, const int* __restrict__ cols, int E,
                          const float* __restrict__ xw, const float* __restrict__ dinv,
                          float* __restrict__ out) {
    int t = blockIdx.x * 256 + threadIdx.x;
    int e = t >> 5;
    if (e >= E) return;
    int g = (t & 31) << 2;
    int r = rows[e], c = cols[e];
    float norm = dinv[r] * dinv[c];
    const float4 v = *reinterpret_cast<const float4*>(xw + r * 128 + g);
    float* o = out + c * 128 + g;
    atomicAdd(o + 0, v.x * norm);
    atomicAdd(o + 1, v.y * norm);
    atomicAdd(o + 2, v.z * norm);
    atomicAdd(o + 3, v.w * norm);
}

__global__ void k_bias_selu(float* __restrict__ out, const float* __restrict__ b, int N) {
    int i = blockIdx.x * 256 + threadIdx.x;
    if (i < N * 128) {
        out[i] = selu_f(out[i] + b[i & 127]);
    }
}

// ---------- onera transform ----------
__global__ void k_transform(const float* __restrict__ pos, float* __restrict__ tp, int n) {
    int i = blockIdx.x * 256 + threadIdx.x;
    if (i < n) {
        float x = pos[i * 3 + 0], y = pos[i * 3 + 1], z = pos[i * 3 + 2];
        float nx = x - TAN30f * y;
        float f = 1.0f + (1.0f / 0.56f - 1.0f) * (y / 1.1963f);
        tp[i * 3 + 0] = nx * f;
        tp[i * 3 + 1] = y * f;
        tp[i * 3 + 2] = z * f;
    }
}

// ---------- brute-force knn (k=3) ----------
#define KNN_TILE 512
__global__ __launch_bounds__(256) void k_knn(const float* __restrict__ tpq, int Nq,
                                             const float* __restrict__ tpx, int Nx,
                                             int* __restrict__ oidx, float* __restrict__ ow) {
    int q = blockIdx.x * 256 + threadIdx.x;
    float qx = 0, qy = 0, qz = 0, q2 = 0;
    if (q < Nq) {
        qx = tpq[q * 3]; qy = tpq[q * 3 + 1]; qz = tpq[q * 3 + 2];
        q2 = qx * qx + qy * qy + qz * qz;
    }
    float b0 = 3.4e38f, b1 = 3.4e38f, b2 = 3.4e38f;
    int i0 = 0, i1 = 0, i2 = 0;
    __shared__ float4 pts[KNN_TILE];

    for (int base = 0; base < Nx; base += KNN_TILE) {
        int cnt = min(KNN_TILE, Nx - base);
        __syncthreads();
        for (int j = threadIdx.x; j < cnt; j += 256) {
            float px = tpx[(base + j) * 3], py = tpx[(base + j) * 3 + 1], pz = tpx[(base + j) * 3 + 2];
            pts[j] = make_float4(px, py, pz, px * px + py * py + pz * pz);
        }
        __syncthreads();
#pragma unroll 4
        for (int j = 0; j < cnt; ++j) {
            float4 p = pts[j];
            float dot = qx * p.x + qy * p.y + qz * p.z;
            float d = (q2 - 2.0f * dot) + p.w;
            int id = base + j;
            if (d < b2) {
                if (d < b1) {
                    b2 = b1; i2 = i1;
                    if (d < b0) { b1 = b0; i1 = i0; b0 = d; i0 = id; }
                    else        { b1 = d;  i1 = id; }
                } else { b2 = d; i2 = id; }
            }
        }
    }
    if (q < Nq) {
        float w0 = 1.0f / fmaxf(b0, 1e-16f);
        float w1 = 1.0f / fmaxf(b1, 1e-16f);
        float w2 = 1.0f / fmaxf(b2, 1e-16f);
        float s = w0 + w1 + w2;
        oidx[q * 3 + 0] = i0; oidx[q * 3 + 1] = i1; oidx[q * 3 + 2] = i2;
        ow[q * 4 + 0] = w0; ow[q * 4 + 1] = w1; ow[q * 4 + 2] = w2; ow[q * 4 + 3] = s;
    }
}

__global__ void k_interp(const float* __restrict__ x, const int* __restrict__ idx,
                         const float* __restrict__ w, float* __restrict__ y, int Nq) {
    int t = blockIdx.x * 256 + threadIdx.x;
    if (t >= Nq * 128) return;
    int j = t >> 7, c = t & 127;
    int i0 = idx[j * 3], i1 = idx[j * 3 + 1], i2 = idx[j * 3 + 2];
    float w0 = w[j * 4], w1 = w[j * 4 + 1], w2 = w[j * 4 + 2], s = w[j * 4 + 3];
    float num = w0 * x[i0 * 128 + c] + w1 * x[i1 * 128 + c] + w2 * x[i2 * 128 + c];
    y[j * 128 + c] = num / s;
}

// ---------- output conv (OC=5) ----------
__global__ __launch_bounds__(256) void k_matmul5(const float* __restrict__ X, const float* __restrict__ P,
                                                 const float* __restrict__ W, float* __restrict__ Y, int N) {
    __shared__ float xs[32][132];
    __shared__ float ws[131 * 5];
    int row0 = blockIdx.x * 32;
    for (int idx = threadIdx.x; idx < 131 * 5; idx += 256) ws[idx] = W[idx];
    for (int idx = threadIdx.x; idx < 32 * 128; idx += 256) {
        int r = idx >> 7, c = idx & 127;
        xs[r][c] = X[(row0 + r) * 128 + c];
    }
    for (int idx = threadIdx.x; idx < 32 * 3; idx += 256) {
        int r = idx / 3, c = idx % 3;
        xs[r][128 + c] = P[(row0 + r) * 3 + c];
    }
    __syncthreads();
    int r = threadIdx.x >> 3;
    int c = threadIdx.x & 7;
    if (c < 5) {
        float acc = 0.0f;
        for (int i = 0; i < 131; ++i) acc = fmaf(xs[r][i], ws[i * 5 + c], acc);
        Y[(row0 + r) * 5 + c] = acc;
    }
}

__global__ void k_selfinit5(const float* __restrict__ xw, const float* __restrict__ dinv,
                            const float* __restrict__ b, float* __restrict__ out, int N) {
    int t = blockIdx.x * 256 + threadIdx.x;
    if (t < N * 5) {
        int r = t / 5, c = t % 5;
        float di = dinv[r];
        out[t] = xw[t] * di * di + b[c];
    }
}

__global__ void k_edge5(const int* __restrict__ rows, const int* __restrict__ cols, int E,
                        const float* __restrict__ xw, const float* __restrict__ dinv,
                        float* __restrict__ out) {
    int t = blockIdx.x * 256 + threadIdx.x;
    int e = t >> 3;
    int c = t & 7;
    if (e >= E || c >= 5) return;
    int r = rows[e], cc = cols[e];
    float norm = dinv[r] * dinv[cc];
    atomicAdd(&out[cc * 5 + c], xw[r * 5 + c] * norm);
}

extern "C" void kernel_launch(void* const* d_in, const int* in_sizes, int n_in,
                              void* d_out, int out_size, void* d_ws, size_t ws_size,
                              hipStream_t stream) {
    const float* latent = (const float*)d_in[0];
    const float* pos0   = (const float*)d_in[1];
    const float* pos1   = (const float*)d_in[2];
    const float* pos2   = (const float*)d_in[3];
    const float* W_lin  = (const float*)d_in[4];
    const float* b_lin  = (const float*)d_in[5];
    const float* W0 = (const float*)d_in[6];  const float* b0 = (const float*)d_in[7];
    const float* W1 = (const float*)d_in[8];  const float* b1 = (const float*)d_in[9];
    const float* W2 = (const float*)d_in[10]; const float* b2 = (const float*)d_in[11];
    const float* W3 = (const float*)d_in[12]; const float* b3 = (const float*)d_in[13];
    const float* W4 = (const float*)d_in[14]; const float* b4 = (const float*)d_in[15];
    const int* ei0 = (const int*)d_in[16];
    const int* ei1 = (const int*)d_in[17];
    const int* ei2 = (const int*)d_in[18];
    float* out = (float*)d_out;

    const int N0 = in_sizes[1] / 3, N1 = in_sizes[2] / 3, N2 = in_sizes[3] / 3;
    const int E0 = in_sizes[16] / 2, E1 = in_sizes[17] / 2, E2 = in_sizes[18] / 2;

    char* wsp = (char*)d_ws;
    auto alloc = [&](size_t bytes) {
        char* p = wsp;
        wsp += (bytes + 255) & ~size_t(255);
        return p;
    };
    float* A    = (float*)alloc((size_t)N2 * 128 * 4);
    float* Bb   = (float*)alloc((size_t)N2 * 128 * 4);
    float* tp0  = (float*)alloc((size_t)N0 * 3 * 4);
    float* tp1  = (float*)alloc((size_t)N1 * 3 * 4);
    float* tp2  = (float*)alloc((size_t)N2 * 3 * 4);
    float* dinv = (float*)alloc((size_t)N2 * 4);
    int*   kidx = (int*)  alloc((size_t)N2 * 3 * 4);
    float* kw   = (float*)alloc((size_t)N2 * 4 * 4);
    float* xw5  = (float*)alloc((size_t)N2 * 5 * 4);

    auto cdiv = [](int a, int b) { return (a + b - 1) / b; };

    // position transforms
    k_transform<<<cdiv(N0, 256), 256, 0, stream>>>(pos0, tp0, N0);
    k_transform<<<cdiv(N1, 256), 256, 0, stream>>>(pos1, tp1, N1);
    k_transform<<<cdiv(N2, 256), 256, 0, stream>>>(pos2, tp2, N2);

    // x = selu(latent @ W_lin + b_lin)  -> A
    k_matmul128<64, false, true><<<cdiv(N0, 16), 256, 0, stream>>>(latent, nullptr, W_lin, b_lin, A, N0);

    auto conv128 = [&](const float* x, const float* pos, const int* ei, int E, int N,
                       const float* W, const float* b, float* xw, float* outb) {
        k_fill<<<cdiv(N, 256), 256, 0, stream>>>(dinv, 1.0f, N);
        k_count<<<cdiv(E, 256), 256, 0, stream>>>(ei + E, E, dinv);
        k_rsqrt<<<cdiv(N, 256), 256, 0, stream>>>(dinv, N);
        k_matmul128<128, true, false><<<cdiv(N, 16), 256, 0, stream>>>(x, pos, W, nullptr, xw, N);
        k_selfinit<<<cdiv(N * 128, 256), 256, 0, stream>>>(xw, dinv, outb, N);
        k_edge128<<<cdiv(E * 32, 256), 256, 0, stream>>>(ei, ei + E, E, xw, dinv, outb);
        k_bias_selu<<<cdiv(N * 128, 256), 256, 0, stream>>>(outb, b, N);
    };

    // two convs at level 0 (x in A, xw in B, out back to A)
    conv128(A, pos0, ei0, E0, N0, W0, b0, Bb, A);
    conv128(A, pos0, ei0, E0, N0, W1, b1, Bb, A);

    // pool 0 -> 1
    k_knn<<<cdiv(N1, 256), 256, 0, stream>>>(tp1, N1, tp0, N0, kidx, kw);
    k_interp<<<cdiv(N1 * 128, 256), 256, 0, stream>>>(A, kidx, kw, Bb, N1);

    // conv at level 1 (x in B, xw in A, out back to B)
    conv128(Bb, pos1, ei1, E1, N1, W2, b2, A, Bb);

    // pool 1 -> 2
    k_knn<<<cdiv(N2, 256), 256, 0, stream>>>(tp2, N2, tp1, N1, kidx, kw);
    k_interp<<<cdiv(N2 * 128, 256), 256, 0, stream>>>(Bb, kidx, kw, A, N2);

    // conv at level 2 (x in A, xw in B, out back to A)
    conv128(A, pos2, ei2, E2, N2, W3, b3, Bb, A);

    // output conv (OC=5), reuses dinv for level-2 graph computed by conv above
    k_matmul5<<<cdiv(N2, 32), 256, 0, stream>>>(A, pos2, W4, xw5, N2);
    k_selfinit5<<<cdiv(N2 * 5, 256), 256, 0, stream>>>(xw5, dinv, b4, out, N2);
    k_edge5<<<cdiv(E2 * 8, 256), 256, 0, stream>>>(ei2, ei2 + E2, E2, xw5, dinv, out);
}

// Round 2
// 3808.357 us; speedup vs baseline: 1.6880x; 1.6880x over previous
//
#include <hip/hip_runtime.h>
#include <math.h>

#define TAN30f 0.57735026918962576f
#define SELU_SCALE 1.0507009873554805f
#define SELU_ALPHA 1.6732632423543772f

__device__ __forceinline__ float selu_f(float x) {
    return SELU_SCALE * (x > 0.0f ? x : SELU_ALPHA * expm1f(x));
}

// ---------- dense matmul: Y[N,128] = concat(X[N,FIC], P[N,3]?) @ W ----------
template<int FIC, bool HAS_POS, bool BIAS_SELU>
__global__ __launch_bounds__(256) void k_matmul128(
    const float* __restrict__ X, const float* __restrict__ P,
    const float* __restrict__ W, const float* __restrict__ bias,
    float* __restrict__ Y, int N)
{
    constexpr int ICT = FIC + (HAS_POS ? 3 : 0);
    __shared__ float xs[16][ICT + 1];
    int row0 = blockIdx.x * 16;

    for (int idx = threadIdx.x; idx < 16 * FIC; idx += 256) {
        int r = idx / FIC, c = idx % FIC;
        int gr = row0 + r;
        xs[r][c] = (gr < N) ? X[gr * FIC + c] : 0.0f;
    }
    if (HAS_POS) {
        for (int idx = threadIdx.x; idx < 16 * 3; idx += 256) {
            int r = idx / 3, c = idx % 3;
            int gr = row0 + r;
            xs[r][FIC + c] = (gr < N) ? P[gr * 3 + c] : 0.0f;
        }
    }
    __syncthreads();

    int col = threadIdx.x & 127;
    int half = threadIdx.x >> 7;
    float acc[8];
#pragma unroll
    for (int r = 0; r < 8; ++r) acc[r] = 0.0f;

#pragma unroll 4
    for (int i = 0; i < ICT; ++i) {
        float wv = W[i * 128 + col];
#pragma unroll
        for (int r = 0; r < 8; ++r)
            acc[r] = fmaf(xs[half * 8 + r][i], wv, acc[r]);
    }

    float bv = BIAS_SELU ? bias[col] : 0.0f;
#pragma unroll
    for (int r = 0; r < 8; ++r) {
        int gr = row0 + half * 8 + r;
        if (gr < N) {
            float v = acc[r];
            if (BIAS_SELU) v = selu_f(v + bv);
            Y[gr * 128 + col] = v;
        }
    }
}

// ---------- small helpers ----------
__global__ void k_fill(float* __restrict__ p, float v, int n) {
    int i = blockIdx.x * 256 + threadIdx.x;
    if (i < n) p[i] = v;
}

__global__ void k_count(const int* __restrict__ col, int E, float* __restrict__ deg) {
    int i = blockIdx.x * 256 + threadIdx.x;
    if (i < E) atomicAdd(&deg[col[i]], 1.0f);
}

__global__ void k_rsqrt(float* __restrict__ p, int n) {
    int i = blockIdx.x * 256 + threadIdx.x;
    if (i < n) p[i] = rsqrtf(p[i]);
}

__global__ void k_selfinit(const float* __restrict__ xw, const float* __restrict__ dinv,
                           float* __restrict__ out, int N) {
    int i = blockIdx.x * 256 + threadIdx.x;
    if (i < N * 128) {
        int r = i >> 7;
        float di = dinv[r];
        out[i] = xw[i] * di * di;
    }
}

__global__ void k_edge128(const int* __restrict__ rows, const int* __restrict__ cols, int E,
                          const float* __restrict__ xw, const float* __restrict__ dinv,
                          float* __restrict__ out) {
    int t = blockIdx.x * 256 + threadIdx.x;
    int e = t >> 5;
    if (e >= E) return;
    int g = (t & 31) << 2;
    int r = rows[e], c = cols[e];
    float norm = dinv[r] * dinv[c];
    const float4 v = *reinterpret_cast<const float4*>(xw + r * 128 + g);
    float* o = out + c * 128 + g;
    atomicAdd(o + 0, v.x * norm);
    atomicAdd(o + 1, v.y * norm);
    atomicAdd(o + 2, v.z * norm);
    atomicAdd(o + 3, v.w * norm);
}

__global__ void k_bias_selu(float* __restrict__ out, const float* __restrict__ b, int N) {
    int i = blockIdx.x * 256 + threadIdx.x;
    if (i < N * 128) {
        out[i] = selu_f(out[i] + b[i & 127]);
    }
}

// ---------- onera transform ----------
__global__ void k_transform(const float* __restrict__ pos, float* __restrict__ tp, int n) {
    int i = blockIdx.x * 256 + threadIdx.x;
    if (i < n) {
        float x = pos[i * 3 + 0], y = pos[i * 3 + 1], z = pos[i * 3 + 2];
        float nx = x - TAN30f * y;
        float f = 1.0f + (1.0f / 0.56f - 1.0f) * (y / 1.1963f);
        tp[i * 3 + 0] = nx * f;
        tp[i * 3 + 1] = y * f;
        tp[i * 3 + 2] = z * f;
    }
}

// ---------- brute-force knn (k=3), chunked over the reference set ----------
// Phase 1: each block handles 256 queries x one chunk of X; writes partial top-3.
#define KNN_TILE 512
__global__ __launch_bounds__(256) void k_knn_part(
    const float* __restrict__ tpq, int Nq,
    const float* __restrict__ tpx, int Nx, int chunkLen,
    float* __restrict__ pd, int* __restrict__ pi)
{
    int q = blockIdx.x * 256 + threadIdx.x;
    int x0 = blockIdx.y * chunkLen;
    int x1 = min(x0 + chunkLen, Nx);

    float qx = 0, qy = 0, qz = 0, q2 = 0;
    if (q < Nq) {
        qx = tpq[q * 3]; qy = tpq[q * 3 + 1]; qz = tpq[q * 3 + 2];
        q2 = qx * qx + qy * qy + qz * qz;
    }
    float b0 = 3.4e38f, b1 = 3.4e38f, b2 = 3.4e38f;
    int i0 = 0, i1 = 0, i2 = 0;
    __shared__ float4 pts[KNN_TILE];

    for (int base = x0; base < x1; base += KNN_TILE) {
        int cnt = min(KNN_TILE, x1 - base);
        __syncthreads();
        for (int j = threadIdx.x; j < cnt; j += 256) {
            float px = tpx[(base + j) * 3], py = tpx[(base + j) * 3 + 1], pz = tpx[(base + j) * 3 + 2];
            pts[j] = make_float4(px, py, pz, px * px + py * py + pz * pz);
        }
        __syncthreads();
#pragma unroll 8
        for (int j = 0; j < cnt; ++j) {
            float4 p = pts[j];
            float dot = qx * p.x + qy * p.y + qz * p.z;
            float d = (q2 - 2.0f * dot) + p.w;
            int id = base + j;
            if (d < b2) {
                if (d < b1) {
                    b2 = b1; i2 = i1;
                    if (d < b0) { b1 = b0; i1 = i0; b0 = d; i0 = id; }
                    else        { b1 = d;  i1 = id; }
                } else { b2 = d; i2 = id; }
            }
        }
    }
    if (q < Nq) {
        size_t o = ((size_t)blockIdx.y * Nq + q) * 3;
        pd[o + 0] = b0; pd[o + 1] = b1; pd[o + 2] = b2;
        pi[o + 0] = i0; pi[o + 1] = i1; pi[o + 2] = i2;
    }
}

// Phase 2: merge the per-chunk sorted top-3 lists (stable: earlier chunk wins ties).
__global__ void k_knn_merge(const float* __restrict__ pd, const int* __restrict__ pi,
                            int Nq, int nchunk,
                            int* __restrict__ oidx, float* __restrict__ ow)
{
    int q = blockIdx.x * 256 + threadIdx.x;
    if (q >= Nq) return;
    size_t o = (size_t)q * 3;
    float b0 = pd[o], b1 = pd[o + 1], b2 = pd[o + 2];
    int   i0 = pi[o], i1 = pi[o + 1], i2 = pi[o + 2];
    for (int c = 1; c < nchunk; ++c) {
        size_t oc = ((size_t)c * Nq + q) * 3;
#pragma unroll 3
        for (int k = 0; k < 3; ++k) {
            float d = pd[oc + k];
            int  id = pi[oc + k];
            if (d < b2) {
                if (d < b1) {
                    b2 = b1; i2 = i1;
                    if (d < b0) { b1 = b0; i1 = i0; b0 = d; i0 = id; }
                    else        { b1 = d;  i1 = id; }
                } else { b2 = d; i2 = id; }
            }
        }
    }
    float w0 = 1.0f / fmaxf(b0, 1e-16f);
    float w1 = 1.0f / fmaxf(b1, 1e-16f);
    float w2 = 1.0f / fmaxf(b2, 1e-16f);
    float s = w0 + w1 + w2;
    oidx[q * 3 + 0] = i0; oidx[q * 3 + 1] = i1; oidx[q * 3 + 2] = i2;
    ow[q * 4 + 0] = w0; ow[q * 4 + 1] = w1; ow[q * 4 + 2] = w2; ow[q * 4 + 3] = s;
}

__global__ void k_interp(const float* __restrict__ x, const int* __restrict__ idx,
                         const float* __restrict__ w, float* __restrict__ y, int Nq) {
    int t = blockIdx.x * 256 + threadIdx.x;
    if (t >= Nq * 128) return;
    int j = t >> 7, c = t & 127;
    int i0 = idx[j * 3], i1 = idx[j * 3 + 1], i2 = idx[j * 3 + 2];
    float w0 = w[j * 4], w1 = w[j * 4 + 1], w2 = w[j * 4 + 2], s = w[j * 4 + 3];
    float num = w0 * x[i0 * 128 + c] + w1 * x[i1 * 128 + c] + w2 * x[i2 * 128 + c];
    y[j * 128 + c] = num / s;
}

// ---------- output conv (OC=5) ----------
__global__ __launch_bounds__(256) void k_matmul5(const float* __restrict__ X, const float* __restrict__ P,
                                                 const float* __restrict__ W, float* __restrict__ Y, int N) {
    __shared__ float xs[32][132];
    __shared__ float ws[131 * 5];
    int row0 = blockIdx.x * 32;
    for (int idx = threadIdx.x; idx < 131 * 5; idx += 256) ws[idx] = W[idx];
    for (int idx = threadIdx.x; idx < 32 * 128; idx += 256) {
        int r = idx >> 7, c = idx & 127;
        xs[r][c] = X[(row0 + r) * 128 + c];
    }
    for (int idx = threadIdx.x; idx < 32 * 3; idx += 256) {
        int r = idx / 3, c = idx % 3;
        xs[r][128 + c] = P[(row0 + r) * 3 + c];
    }
    __syncthreads();
    int r = threadIdx.x >> 3;
    int c = threadIdx.x & 7;
    if (c < 5) {
        float acc = 0.0f;
        for (int i = 0; i < 131; ++i) acc = fmaf(xs[r][i], ws[i * 5 + c], acc);
        Y[(row0 + r) * 5 + c] = acc;
    }
}

__global__ void k_selfinit5(const float* __restrict__ xw, const float* __restrict__ dinv,
                            const float* __restrict__ b, float* __restrict__ out, int N) {
    int t = blockIdx.x * 256 + threadIdx.x;
    if (t < N * 5) {
        int r = t / 5, c = t % 5;
        float di = dinv[r];
        out[t] = xw[t] * di * di + b[c];
    }
}

__global__ void k_edge5(const int* __restrict__ rows, const int* __restrict__ cols, int E,
                        const float* __restrict__ xw, const float* __restrict__ dinv,
                        float* __restrict__ out) {
    int t = blockIdx.x * 256 + threadIdx.x;
    int e = t >> 3;
    int c = t & 7;
    if (e >= E || c >= 5) return;
    int r = rows[e], cc = cols[e];
    float norm = dinv[r] * dinv[cc];
    atomicAdd(&out[cc * 5 + c], xw[r * 5 + c] * norm);
}

extern "C" void kernel_launch(void* const* d_in, const int* in_sizes, int n_in,
                              void* d_out, int out_size, void* d_ws, size_t ws_size,
                              hipStream_t stream) {
    const float* latent = (const float*)d_in[0];
    const float* pos0   = (const float*)d_in[1];
    const float* pos1   = (const float*)d_in[2];
    const float* pos2   = (const float*)d_in[3];
    const float* W_lin  = (const float*)d_in[4];
    const float* b_lin  = (const float*)d_in[5];
    const float* W0 = (const float*)d_in[6];  const float* b0 = (const float*)d_in[7];
    const float* W1 = (const float*)d_in[8];  const float* b1 = (const float*)d_in[9];
    const float* W2 = (const float*)d_in[10]; const float* b2 = (const float*)d_in[11];
    const float* W3 = (const float*)d_in[12]; const float* b3 = (const float*)d_in[13];
    const float* W4 = (const float*)d_in[14]; const float* b4 = (const float*)d_in[15];
    const int* ei0 = (const int*)d_in[16];
    const int* ei1 = (const int*)d_in[17];
    const int* ei2 = (const int*)d_in[18];
    float* out = (float*)d_out;

    const int N0 = in_sizes[1] / 3, N1 = in_sizes[2] / 3, N2 = in_sizes[3] / 3;
    const int E0 = in_sizes[16] / 2, E1 = in_sizes[17] / 2, E2 = in_sizes[18] / 2;
    const int NCHUNK = 8;

    char* wsp = (char*)d_ws;
    auto alloc = [&](size_t bytes) {
        char* p = wsp;
        wsp += (bytes + 255) & ~size_t(255);
        return p;
    };
    float* A     = (float*)alloc((size_t)N2 * 128 * 4);
    float* Bb    = (float*)alloc((size_t)N2 * 128 * 4);
    float* tp0   = (float*)alloc((size_t)N0 * 3 * 4);
    float* tp1   = (float*)alloc((size_t)N1 * 3 * 4);
    float* tp2   = (float*)alloc((size_t)N2 * 3 * 4);
    float* dinv0 = (float*)alloc((size_t)N0 * 4);
    float* dinv1 = (float*)alloc((size_t)N1 * 4);
    float* dinv2 = (float*)alloc((size_t)N2 * 4);
    int*   kidx  = (int*)  alloc((size_t)N2 * 3 * 4);
    float* kw    = (float*)alloc((size_t)N2 * 4 * 4);
    float* ppd   = (float*)alloc((size_t)NCHUNK * N2 * 3 * 4);
    int*   ppi   = (int*)  alloc((size_t)NCHUNK * N2 * 3 * 4);
    float* xw5   = (float*)alloc((size_t)N2 * 5 * 4);

    auto cdiv = [](int a, int b) { return (a + b - 1) / b; };

    // position transforms
    k_transform<<<cdiv(N0, 256), 256, 0, stream>>>(pos0, tp0, N0);
    k_transform<<<cdiv(N1, 256), 256, 0, stream>>>(pos1, tp1, N1);
    k_transform<<<cdiv(N2, 256), 256, 0, stream>>>(pos2, tp2, N2);

    // degree -> dinv per level (level-0 graph used by two convs)
    auto make_dinv = [&](const int* ei, int E, int N, float* dv) {
        k_fill<<<cdiv(N, 256), 256, 0, stream>>>(dv, 1.0f, N);
        k_count<<<cdiv(E, 256), 256, 0, stream>>>(ei + E, E, dv);
        k_rsqrt<<<cdiv(N, 256), 256, 0, stream>>>(dv, N);
    };
    make_dinv(ei0, E0, N0, dinv0);
    make_dinv(ei1, E1, N1, dinv1);
    make_dinv(ei2, E2, N2, dinv2);

    // x = selu(latent @ W_lin + b_lin)  -> A
    k_matmul128<64, false, true><<<cdiv(N0, 16), 256, 0, stream>>>(latent, nullptr, W_lin, b_lin, A, N0);

    auto conv128 = [&](const float* x, const float* pos, const int* ei, int E, int N,
                       const float* dv, const float* W, const float* b, float* xw, float* outb) {
        k_matmul128<128, true, false><<<cdiv(N, 16), 256, 0, stream>>>(x, pos, W, nullptr, xw, N);
        k_selfinit<<<cdiv(N * 128, 256), 256, 0, stream>>>(xw, dv, outb, N);
        k_edge128<<<cdiv(E * 32, 256), 256, 0, stream>>>(ei, ei + E, E, xw, dv, outb);
        k_bias_selu<<<cdiv(N * 128, 256), 256, 0, stream>>>(outb, b, N);
    };

    auto knn = [&](const float* tpq, int Nq, const float* tpx, int Nx) {
        int chunkLen = cdiv(Nx, NCHUNK);
        dim3 grid(cdiv(Nq, 256), NCHUNK);
        k_knn_part<<<grid, 256, 0, stream>>>(tpq, Nq, tpx, Nx, chunkLen, ppd, ppi);
        k_knn_merge<<<cdiv(Nq, 256), 256, 0, stream>>>(ppd, ppi, Nq, NCHUNK, kidx, kw);
    };

    // two convs at level 0 (x in A, xw in B, out back to A)
    conv128(A, pos0, ei0, E0, N0, dinv0, W0, b0, Bb, A);
    conv128(A, pos0, ei0, E0, N0, dinv0, W1, b1, Bb, A);

    // pool 0 -> 1
    knn(tp1, N1, tp0, N0);
    k_interp<<<cdiv(N1 * 128, 256), 256, 0, stream>>>(A, kidx, kw, Bb, N1);

    // conv at level 1 (x in B, xw in A, out back to B)
    conv128(Bb, pos1, ei1, E1, N1, dinv1, W2, b2, A, Bb);

    // pool 1 -> 2
    knn(tp2, N2, tp1, N1);
    k_interp<<<cdiv(N2 * 128, 256), 256, 0, stream>>>(Bb, kidx, kw, A, N2);

    // conv at level 2 (x in A, xw in B, out back to A)
    conv128(A, pos2, ei2, E2, N2, dinv2, W3, b3, Bb, A);

    // output conv (OC=5)
    k_matmul5<<<cdiv(N2, 32), 256, 0, stream>>>(A, pos2, W4, xw5, N2);
    k_selfinit5<<<cdiv(N2 * 5, 256), 256, 0, stream>>>(xw5, dinv2, b4, out, N2);
    k_edge5<<<cdiv(E2 * 8, 256), 256, 0, stream>>>(ei2, ei2 + E2, E2, xw5, dinv2, out);
}

// Round 3
// 1782.142 us; speedup vs baseline: 3.6072x; 2.1370x over previous
//
#include <hip/hip_runtime.h>
#include <math.h>

#define TAN30f 0.57735026918962576f
#define SELU_SCALE 1.0507009873554805f
#define SELU_ALPHA 1.6732632423543772f

__device__ __forceinline__ float selu_f(float x) {
    return SELU_SCALE * (x > 0.0f ? x : SELU_ALPHA * expm1f(x));
}

// ---------- dense matmul: Y[N,128] = concat(X[N,FIC], P[N,3]?) @ W ----------
// If ROWSCALE, multiplies each output row by rs[row] (GCN dinv pre-scale).
template<int FIC, bool HAS_POS, bool BIAS_SELU, bool ROWSCALE>
__global__ __launch_bounds__(256) void k_matmul128(
    const float* __restrict__ X, const float* __restrict__ P,
    const float* __restrict__ W, const float* __restrict__ bias,
    const float* __restrict__ rs,
    float* __restrict__ Y, int N)
{
    constexpr int ICT = FIC + (HAS_POS ? 3 : 0);
    __shared__ float xs[16][ICT + 1];
    int row0 = blockIdx.x * 16;

    for (int idx = threadIdx.x; idx < 16 * FIC; idx += 256) {
        int r = idx / FIC, c = idx % FIC;
        int gr = row0 + r;
        xs[r][c] = (gr < N) ? X[gr * FIC + c] : 0.0f;
    }
    if (HAS_POS) {
        for (int idx = threadIdx.x; idx < 16 * 3; idx += 256) {
            int r = idx / 3, c = idx % 3;
            int gr = row0 + r;
            xs[r][FIC + c] = (gr < N) ? P[gr * 3 + c] : 0.0f;
        }
    }
    __syncthreads();

    int col = threadIdx.x & 127;
    int half = threadIdx.x >> 7;
    float acc[8];
#pragma unroll
    for (int r = 0; r < 8; ++r) acc[r] = 0.0f;

#pragma unroll 4
    for (int i = 0; i < ICT; ++i) {
        float wv = W[i * 128 + col];
#pragma unroll
        for (int r = 0; r < 8; ++r)
            acc[r] = fmaf(xs[half * 8 + r][i], wv, acc[r]);
    }

    float bv = BIAS_SELU ? bias[col] : 0.0f;
#pragma unroll
    for (int r = 0; r < 8; ++r) {
        int gr = row0 + half * 8 + r;
        if (gr < N) {
            float v = acc[r];
            if (BIAS_SELU) v = selu_f(v + bv);
            if (ROWSCALE) v *= rs[gr];
            Y[gr * 128 + col] = v;
        }
    }
}

// ---------- CSR build: histogram -> scan -> scatter ----------
__global__ void k_hist(const int* __restrict__ col, int E, int* __restrict__ cnt) {
    int i = blockIdx.x * 256 + threadIdx.x;
    if (i < E) atomicAdd(&cnt[col[i]], 1);
}

__global__ void k_dinv(const int* __restrict__ cnt, float* __restrict__ dv, int n) {
    int i = blockIdx.x * 256 + threadIdx.x;
    if (i < n) dv[i] = rsqrtf((float)cnt[i] + 1.0f);  // +1 self loop
}

// exclusive scan, 1024 elements per block (256 thr x 4)
__global__ __launch_bounds__(256) void k_scan1(const int* __restrict__ in, int* __restrict__ out,
                                               int* __restrict__ bsum, int n) {
    __shared__ int s[256];
    int tid = threadIdx.x;
    int base = blockIdx.x * 1024 + tid * 4;
    int a[4];
#pragma unroll
    for (int k = 0; k < 4; ++k) a[k] = (base + k < n) ? in[base + k] : 0;
    int t = a[0] + a[1] + a[2] + a[3];
    s[tid] = t;
    __syncthreads();
    for (int off = 1; off < 256; off <<= 1) {
        int x = (tid >= off) ? s[tid - off] : 0;
        __syncthreads();
        s[tid] += x;
        __syncthreads();
    }
    int run = s[tid] - t;
#pragma unroll
    for (int k = 0; k < 4; ++k) {
        if (base + k < n) out[base + k] = run;
        run += a[k];
    }
    if (tid == 255) bsum[blockIdx.x] = s[255];
}

__global__ void k_scan2(int* __restrict__ bsum, int nb) {
    if (threadIdx.x == 0 && blockIdx.x == 0) {
        int run = 0;
        for (int i = 0; i < nb; ++i) { int v = bsum[i]; bsum[i] = run; run += v; }
    }
}

__global__ void k_scan3(int* __restrict__ rowptr, int* __restrict__ cur,
                        const int* __restrict__ bsum, int n, int E) {
    int i = blockIdx.x * 256 + threadIdx.x;
    if (i < n) {
        int v = rowptr[i] + bsum[i >> 10];
        rowptr[i] = v;
        cur[i] = v;
    }
    if (i == 0) rowptr[n] = E;
}

__global__ void k_scatter(const int* __restrict__ rows, const int* __restrict__ cols, int E,
                          int* __restrict__ cur, int* __restrict__ csr) {
    int e = blockIdx.x * 256 + threadIdx.x;
    if (e < E) {
        int p = atomicAdd(&cur[cols[e]], 1);
        csr[p] = rows[e];
    }
}

// ---------- CSR gather aggregation, fused self-loop + dinv + bias + selu ----------
__global__ __launch_bounds__(256) void k_gather128(
    const int* __restrict__ rowptr, const int* __restrict__ csr,
    const float* __restrict__ xws, const float* __restrict__ dv,
    const float* __restrict__ bias, float* __restrict__ out, int N)
{
    int t = blockIdx.x * 256 + threadIdx.x;
    int node = t >> 7, ch = t & 127;
    if (node >= N) return;
    int s = rowptr[node], e = rowptr[node + 1];
    float acc = xws[(size_t)node * 128 + ch];  // self loop (already *dinv[node])
    for (int i = s; i < e; ++i) {
        int src = csr[i];
        acc += xws[(size_t)src * 128 + ch];
    }
    float v = acc * dv[node] + bias[ch];
    out[(size_t)node * 128 + ch] = selu_f(v);
}

__global__ __launch_bounds__(256) void k_gather5(
    const int* __restrict__ rowptr, const int* __restrict__ csr,
    const float* __restrict__ xws, const float* __restrict__ dv,
    const float* __restrict__ bias, float* __restrict__ out, int N)
{
    int t = blockIdx.x * 256 + threadIdx.x;
    int node = t >> 3, ch = t & 7;
    if (node >= N || ch >= 5) return;
    int s = rowptr[node], e = rowptr[node + 1];
    float acc = xws[(size_t)node * 5 + ch];
    for (int i = s; i < e; ++i) {
        int src = csr[i];
        acc += xws[(size_t)src * 5 + ch];
    }
    out[(size_t)node * 5 + ch] = acc * dv[node] + bias[ch];
}

// ---------- onera transform ----------
__global__ void k_transform(const float* __restrict__ pos, float* __restrict__ tp, int n) {
    int i = blockIdx.x * 256 + threadIdx.x;
    if (i < n) {
        float x = pos[i * 3 + 0], y = pos[i * 3 + 1], z = pos[i * 3 + 2];
        float nx = x - TAN30f * y;
        float f = 1.0f + (1.0f / 0.56f - 1.0f) * (y / 1.1963f);
        tp[i * 3 + 0] = nx * f;
        tp[i * 3 + 1] = y * f;
        tp[i * 3 + 2] = z * f;
    }
}

// ---------- brute-force knn (k=3), chunked over the reference set ----------
#define KNN_TILE 512
__global__ __launch_bounds__(256) void k_knn_part(
    const float* __restrict__ tpq, int Nq,
    const float* __restrict__ tpx, int Nx, int chunkLen,
    float* __restrict__ pd, int* __restrict__ pi)
{
    int q = blockIdx.x * 256 + threadIdx.x;
    int x0 = blockIdx.y * chunkLen;
    int x1 = min(x0 + chunkLen, Nx);

    float qx = 0, qy = 0, qz = 0, q2 = 0;
    if (q < Nq) {
        qx = tpq[q * 3]; qy = tpq[q * 3 + 1]; qz = tpq[q * 3 + 2];
        q2 = qx * qx + qy * qy + qz * qz;
    }
    float b0 = 3.4e38f, b1 = 3.4e38f, b2 = 3.4e38f;
    int i0 = 0, i1 = 0, i2 = 0;
    __shared__ float4 pts[KNN_TILE];

    for (int base = x0; base < x1; base += KNN_TILE) {
        int cnt = min(KNN_TILE, x1 - base);
        __syncthreads();
        for (int j = threadIdx.x; j < cnt; j += 256) {
            float px = tpx[(base + j) * 3], py = tpx[(base + j) * 3 + 1], pz = tpx[(base + j) * 3 + 2];
            pts[j] = make_float4(px, py, pz, px * px + py * py + pz * pz);
        }
        __syncthreads();
#pragma unroll 8
        for (int j = 0; j < cnt; ++j) {
            float4 p = pts[j];
            float dot = qx * p.x + qy * p.y + qz * p.z;
            float d = (q2 - 2.0f * dot) + p.w;
            int id = base + j;
            if (d < b2) {
                if (d < b1) {
                    b2 = b1; i2 = i1;
                    if (d < b0) { b1 = b0; i1 = i0; b0 = d; i0 = id; }
                    else        { b1 = d;  i1 = id; }
                } else { b2 = d; i2 = id; }
            }
        }
    }
    if (q < Nq) {
        size_t o = ((size_t)blockIdx.y * Nq + q) * 3;
        pd[o + 0] = b0; pd[o + 1] = b1; pd[o + 2] = b2;
        pi[o + 0] = i0; pi[o + 1] = i1; pi[o + 2] = i2;
    }
}

__global__ void k_knn_merge(const float* __restrict__ pd, const int* __restrict__ pi,
                            int Nq, int nchunk,
                            int* __restrict__ oidx, float* __restrict__ ow)
{
    int q = blockIdx.x * 256 + threadIdx.x;
    if (q >= Nq) return;
    size_t o = (size_t)q * 3;
    float b0 = pd[o], b1 = pd[o + 1], b2 = pd[o + 2];
    int   i0 = pi[o], i1 = pi[o + 1], i2 = pi[o + 2];
    for (int c = 1; c < nchunk; ++c) {
        size_t oc = ((size_t)c * Nq + q) * 3;
#pragma unroll 3
        for (int k = 0; k < 3; ++k) {
            float d = pd[oc + k];
            int  id = pi[oc + k];
            if (d < b2) {
                if (d < b1) {
                    b2 = b1; i2 = i1;
                    if (d < b0) { b1 = b0; i1 = i0; b0 = d; i0 = id; }
                    else        { b1 = d;  i1 = id; }
                } else { b2 = d; i2 = id; }
            }
        }
    }
    float w0 = 1.0f / fmaxf(b0, 1e-16f);
    float w1 = 1.0f / fmaxf(b1, 1e-16f);
    float w2 = 1.0f / fmaxf(b2, 1e-16f);
    float s = w0 + w1 + w2;
    oidx[q * 3 + 0] = i0; oidx[q * 3 + 1] = i1; oidx[q * 3 + 2] = i2;
    ow[q * 4 + 0] = w0; ow[q * 4 + 1] = w1; ow[q * 4 + 2] = w2; ow[q * 4 + 3] = s;
}

__global__ void k_interp(const float* __restrict__ x, const int* __restrict__ idx,
                         const float* __restrict__ w, float* __restrict__ y, int Nq) {
    int t = blockIdx.x * 256 + threadIdx.x;
    if (t >= Nq * 128) return;
    int j = t >> 7, c = t & 127;
    int i0 = idx[j * 3], i1 = idx[j * 3 + 1], i2 = idx[j * 3 + 2];
    float w0 = w[j * 4], w1 = w[j * 4 + 1], w2 = w[j * 4 + 2], s = w[j * 4 + 3];
    float num = w0 * x[i0 * 128 + c] + w1 * x[i1 * 128 + c] + w2 * x[i2 * 128 + c];
    y[j * 128 + c] = num / s;
}

// ---------- output conv matmul (OC=5), row-scaled by dinv ----------
__global__ __launch_bounds__(256) void k_matmul5(const float* __restrict__ X, const float* __restrict__ P,
                                                 const float* __restrict__ W, const float* __restrict__ rs,
                                                 float* __restrict__ Y, int N) {
    __shared__ float xs[32][132];
    __shared__ float ws[131 * 5];
    int row0 = blockIdx.x * 32;
    for (int idx = threadIdx.x; idx < 131 * 5; idx += 256) ws[idx] = W[idx];
    for (int idx = threadIdx.x; idx < 32 * 128; idx += 256) {
        int r = idx >> 7, c = idx & 127;
        xs[r][c] = X[(size_t)(row0 + r) * 128 + c];
    }
    for (int idx = threadIdx.x; idx < 32 * 3; idx += 256) {
        int r = idx / 3, c = idx % 3;
        xs[r][128 + c] = P[(row0 + r) * 3 + c];
    }
    __syncthreads();
    int r = threadIdx.x >> 3;
    int c = threadIdx.x & 7;
    if (c < 5) {
        float acc = 0.0f;
        for (int i = 0; i < 131; ++i) acc = fmaf(xs[r][i], ws[i * 5 + c], acc);
        Y[(size_t)(row0 + r) * 5 + c] = acc * rs[row0 + r];
    }
}

extern "C" void kernel_launch(void* const* d_in, const int* in_sizes, int n_in,
                              void* d_out, int out_size, void* d_ws, size_t ws_size,
                              hipStream_t stream) {
    const float* latent = (const float*)d_in[0];
    const float* pos0   = (const float*)d_in[1];
    const float* pos1   = (const float*)d_in[2];
    const float* pos2   = (const float*)d_in[3];
    const float* W_lin  = (const float*)d_in[4];
    const float* b_lin  = (const float*)d_in[5];
    const float* W0 = (const float*)d_in[6];  const float* b0 = (const float*)d_in[7];
    const float* W1 = (const float*)d_in[8];  const float* b1 = (const float*)d_in[9];
    const float* W2 = (const float*)d_in[10]; const float* b2 = (const float*)d_in[11];
    const float* W3 = (const float*)d_in[12]; const float* b3 = (const float*)d_in[13];
    const float* W4 = (const float*)d_in[14]; const float* b4 = (const float*)d_in[15];
    const int* ei0 = (const int*)d_in[16];
    const int* ei1 = (const int*)d_in[17];
    const int* ei2 = (const int*)d_in[18];
    float* out = (float*)d_out;

    const int N0 = in_sizes[1] / 3, N1 = in_sizes[2] / 3, N2 = in_sizes[3] / 3;
    const int E0 = in_sizes[16] / 2, E1 = in_sizes[17] / 2, E2 = in_sizes[18] / 2;
    const int NCHUNK = 8;

    char* wsp = (char*)d_ws;
    auto alloc = [&](size_t bytes) {
        char* p = wsp;
        wsp += (bytes + 255) & ~size_t(255);
        return p;
    };
    float* A      = (float*)alloc((size_t)N2 * 128 * 4);
    float* Bb     = (float*)alloc((size_t)N2 * 128 * 4);
    float* tp0    = (float*)alloc((size_t)N0 * 3 * 4);
    float* tp1    = (float*)alloc((size_t)N1 * 3 * 4);
    float* tp2    = (float*)alloc((size_t)N2 * 3 * 4);
    float* dv     = (float*)alloc((size_t)N2 * 4);
    int*   cnt    = (int*)  alloc((size_t)N2 * 4);
    int*   rowptr = (int*)  alloc(((size_t)N2 + 1) * 4);
    int*   cur    = (int*)  alloc((size_t)N2 * 4);
    int*   bsum   = (int*)  alloc(4096);
    int*   csr    = (int*)  alloc((size_t)E2 * 4);
    int*   kidx   = (int*)  alloc((size_t)N2 * 3 * 4);
    float* kw     = (float*)alloc((size_t)N2 * 4 * 4);
    float* ppd    = (float*)alloc((size_t)NCHUNK * N2 * 3 * 4);
    int*   ppi    = (int*)  alloc((size_t)NCHUNK * N2 * 3 * 4);
    float* xw5    = (float*)alloc((size_t)N2 * 5 * 4);

    auto cdiv = [](int a, int b) { return (a + b - 1) / b; };

    // position transforms
    k_transform<<<cdiv(N0, 256), 256, 0, stream>>>(pos0, tp0, N0);
    k_transform<<<cdiv(N1, 256), 256, 0, stream>>>(pos1, tp1, N1);
    k_transform<<<cdiv(N2, 256), 256, 0, stream>>>(pos2, tp2, N2);

    // build CSR + dinv for a graph level (dest-major)
    auto build_graph = [&](const int* ei, int E, int N) {
        const int* cols = ei + E;
        hipMemsetAsync(cnt, 0, (size_t)N * 4, stream);
        k_hist<<<cdiv(E, 256), 256, 0, stream>>>(cols, E, cnt);
        k_dinv<<<cdiv(N, 256), 256, 0, stream>>>(cnt, dv, N);
        int nb = cdiv(N, 1024);
        k_scan1<<<nb, 256, 0, stream>>>(cnt, rowptr, bsum, N);
        k_scan2<<<1, 64, 0, stream>>>(bsum, nb);
        k_scan3<<<cdiv(N, 256), 256, 0, stream>>>(rowptr, cur, bsum, N, E);
        k_scatter<<<cdiv(E, 256), 256, 0, stream>>>(ei, cols, E, cur, csr);
    };

    auto conv128 = [&](const float* x, const float* pos, int N,
                       const float* W, const float* b, float* xws, float* outb) {
        k_matmul128<128, true, false, true><<<cdiv(N, 16), 256, 0, stream>>>(x, pos, W, nullptr, dv, xws, N);
        k_gather128<<<cdiv(N * 128, 256), 256, 0, stream>>>(rowptr, csr, xws, dv, b, outb, N);
    };

    auto knn = [&](const float* tpq, int Nq, const float* tpx, int Nx) {
        int chunkLen = cdiv(Nx, NCHUNK);
        dim3 grid(cdiv(Nq, 256), NCHUNK);
        k_knn_part<<<grid, 256, 0, stream>>>(tpq, Nq, tpx, Nx, chunkLen, ppd, ppi);
        k_knn_merge<<<cdiv(Nq, 256), 256, 0, stream>>>(ppd, ppi, Nq, NCHUNK, kidx, kw);
    };

    // x = selu(latent @ W_lin + b_lin)  -> A
    k_matmul128<64, false, true, false><<<cdiv(N0, 16), 256, 0, stream>>>(latent, nullptr, W_lin, b_lin, nullptr, A, N0);

    // level 0: two convs
    build_graph(ei0, E0, N0);
    conv128(A, pos0, N0, W0, b0, Bb, A);
    conv128(A, pos0, N0, W1, b1, Bb, A);

    // pool 0 -> 1
    knn(tp1, N1, tp0, N0);
    k_interp<<<cdiv(N1 * 128, 256), 256, 0, stream>>>(A, kidx, kw, Bb, N1);

    // level 1 conv (x in B, out back to B)
    build_graph(ei1, E1, N1);
    conv128(Bb, pos1, N1, W2, b2, A, Bb);

    // pool 1 -> 2
    knn(tp2, N2, tp1, N1);
    k_interp<<<cdiv(N2 * 128, 256), 256, 0, stream>>>(Bb, kidx, kw, A, N2);

    // level 2 conv (x in A, out back to A)
    build_graph(ei2, E2, N2);
    conv128(A, pos2, N2, W3, b3, Bb, A);

    // output conv (OC=5) — reuses level-2 CSR/dinv
    k_matmul5<<<cdiv(N2, 32), 256, 0, stream>>>(A, pos2, W4, dv, xw5, N2);
    k_gather5<<<cdiv(N2 * 8, 256), 256, 0, stream>>>(rowptr, csr, xw5, dv, b4, out, N2);
}

// Round 4
// 1715.779 us; speedup vs baseline: 3.7467x; 1.0387x over previous
//
#include <hip/hip_runtime.h>
#include <math.h>

#define TAN30f 0.57735026918962576f
#define SELU_SCALE 1.0507009873554805f
#define SELU_ALPHA 1.6732632423543772f

__device__ __forceinline__ float selu_f(float x) {
    return SELU_SCALE * (x > 0.0f ? x : SELU_ALPHA * expm1f(x));
}

// ---------- dense matmul: Y[N,128] = concat(X[N,FIC], P[N,3]?) @ W ----------
template<int FIC, bool HAS_POS, bool BIAS_SELU, bool ROWSCALE>
__global__ __launch_bounds__(256) void k_matmul128(
    const float* __restrict__ X, const float* __restrict__ P,
    const float* __restrict__ W, const float* __restrict__ bias,
    const float* __restrict__ rs,
    float* __restrict__ Y, int N)
{
    constexpr int ICT = FIC + (HAS_POS ? 3 : 0);
    __shared__ float xs[16][ICT + 1];
    int row0 = blockIdx.x * 16;

    for (int idx = threadIdx.x; idx < 16 * FIC; idx += 256) {
        int r = idx / FIC, c = idx % FIC;
        int gr = row0 + r;
        xs[r][c] = (gr < N) ? X[gr * FIC + c] : 0.0f;
    }
    if (HAS_POS) {
        for (int idx = threadIdx.x; idx < 16 * 3; idx += 256) {
            int r = idx / 3, c = idx % 3;
            int gr = row0 + r;
            xs[r][FIC + c] = (gr < N) ? P[gr * 3 + c] : 0.0f;
        }
    }
    __syncthreads();

    int col = threadIdx.x & 127;
    int half = threadIdx.x >> 7;
    float acc[8];
#pragma unroll
    for (int r = 0; r < 8; ++r) acc[r] = 0.0f;

#pragma unroll 4
    for (int i = 0; i < ICT; ++i) {
        float wv = W[i * 128 + col];
#pragma unroll
        for (int r = 0; r < 8; ++r)
            acc[r] = fmaf(xs[half * 8 + r][i], wv, acc[r]);
    }

    float bv = BIAS_SELU ? bias[col] : 0.0f;
#pragma unroll
    for (int r = 0; r < 8; ++r) {
        int gr = row0 + half * 8 + r;
        if (gr < N) {
            float v = acc[r];
            if (BIAS_SELU) v = selu_f(v + bv);
            if (ROWSCALE) v *= rs[gr];
            Y[gr * 128 + col] = v;
        }
    }
}

// ---------- CSR build: histogram -> scan -> scatter ----------
__global__ void k_hist(const int* __restrict__ col, int E, int* __restrict__ cnt) {
    int i = blockIdx.x * 256 + threadIdx.x;
    if (i < E) atomicAdd(&cnt[col[i]], 1);
}

__global__ void k_dinv(const int* __restrict__ cnt, float* __restrict__ dv, int n) {
    int i = blockIdx.x * 256 + threadIdx.x;
    if (i < n) dv[i] = rsqrtf((float)cnt[i] + 1.0f);  // +1 self loop
}

__global__ __launch_bounds__(256) void k_scan1(const int* __restrict__ in, int* __restrict__ out,
                                               int* __restrict__ bsum, int n) {
    __shared__ int s[256];
    int tid = threadIdx.x;
    int base = blockIdx.x * 1024 + tid * 4;
    int a[4];
#pragma unroll
    for (int k = 0; k < 4; ++k) a[k] = (base + k < n) ? in[base + k] : 0;
    int t = a[0] + a[1] + a[2] + a[3];
    s[tid] = t;
    __syncthreads();
    for (int off = 1; off < 256; off <<= 1) {
        int x = (tid >= off) ? s[tid - off] : 0;
        __syncthreads();
        s[tid] += x;
        __syncthreads();
    }
    int run = s[tid] - t;
#pragma unroll
    for (int k = 0; k < 4; ++k) {
        if (base + k < n) out[base + k] = run;
        run += a[k];
    }
    if (tid == 255) bsum[blockIdx.x] = s[255];
}

__global__ void k_scan2(int* __restrict__ bsum, int nb) {
    if (threadIdx.x == 0 && blockIdx.x == 0) {
        int run = 0;
        for (int i = 0; i < nb; ++i) { int v = bsum[i]; bsum[i] = run; run += v; }
    }
}

__global__ void k_scan3(int* __restrict__ rowptr, int* __restrict__ cur,
                        const int* __restrict__ bsum, int n, int E) {
    int i = blockIdx.x * 256 + threadIdx.x;
    if (i < n) {
        int v = rowptr[i] + bsum[i >> 10];
        rowptr[i] = v;
        cur[i] = v;
    }
    if (i == 0) rowptr[n] = E;
}

__global__ void k_scatter(const int* __restrict__ rows, const int* __restrict__ cols, int E,
                          int* __restrict__ cur, int* __restrict__ csr) {
    int e = blockIdx.x * 256 + threadIdx.x;
    if (e < E) {
        int p = atomicAdd(&cur[cols[e]], 1);
        csr[p] = rows[e];
    }
}

// ---------- CSR gather aggregation, fused self-loop + dinv + bias + selu ----------
__global__ __launch_bounds__(256) void k_gather128(
    const int* __restrict__ rowptr, const int* __restrict__ csr,
    const float* __restrict__ xws, const float* __restrict__ dv,
    const float* __restrict__ bias, float* __restrict__ out, int N)
{
    int t = blockIdx.x * 256 + threadIdx.x;
    int node = t >> 7, ch = t & 127;
    if (node >= N) return;
    int s = rowptr[node], e = rowptr[node + 1];
    float acc = xws[(size_t)node * 128 + ch];
    for (int i = s; i < e; ++i) {
        int src = csr[i];
        acc += xws[(size_t)src * 128 + ch];
    }
    float v = acc * dv[node] + bias[ch];
    out[(size_t)node * 128 + ch] = selu_f(v);
}

__global__ __launch_bounds__(256) void k_gather5(
    const int* __restrict__ rowptr, const int* __restrict__ csr,
    const float* __restrict__ xws, const float* __restrict__ dv,
    const float* __restrict__ bias, float* __restrict__ out, int N)
{
    int t = blockIdx.x * 256 + threadIdx.x;
    int node = t >> 3, ch = t & 7;
    if (node >= N || ch >= 5) return;
    int s = rowptr[node], e = rowptr[node + 1];
    float acc = xws[(size_t)node * 5 + ch];
    for (int i = s; i < e; ++i) {
        int src = csr[i];
        acc += xws[(size_t)src * 5 + ch];
    }
    out[(size_t)node * 5 + ch] = acc * dv[node] + bias[ch];
}

// ---------- onera transform ----------
__global__ void k_transform(const float* __restrict__ pos, float* __restrict__ tp, int n) {
    int i = blockIdx.x * 256 + threadIdx.x;
    if (i < n) {
        float x = pos[i * 3 + 0], y = pos[i * 3 + 1], z = pos[i * 3 + 2];
        float nx = x - TAN30f * y;
        float f = 1.0f + (1.0f / 0.56f - 1.0f) * (y / 1.1963f);
        tp[i * 3 + 0] = nx * f;
        tp[i * 3 + 1] = y * f;
        tp[i * 3 + 2] = z * f;
    }
}

// ---------- brute-force knn (k=3), chunked + query-register-tiled ----------
// Compare in s-space: s = 0.5*|p|^2 - q.p  (monotonic in d per query);
// d = 2*s + |q|^2 recovered at the epilogue.
#define KNN_TILE 512
#define KNN_Q 2
__global__ __launch_bounds__(256) void k_knn_part(
    const float* __restrict__ tpq, int Nq,
    const float* __restrict__ tpx, int Nx, int chunkLen,
    float* __restrict__ pd, int* __restrict__ pi)
{
    int q0 = blockIdx.x * (256 * KNN_Q) + threadIdx.x;
    int x0 = blockIdx.y * chunkLen;
    int x1 = min(x0 + chunkLen, Nx);

    float qx[KNN_Q], qy[KNN_Q], qz[KNN_Q], q2[KNN_Q];
    float b0[KNN_Q], b1[KNN_Q], b2[KNN_Q];
    int i0[KNN_Q], i1[KNN_Q], i2[KNN_Q];
#pragma unroll
    for (int r = 0; r < KNN_Q; ++r) {
        int q = q0 + r * 256;
        if (q < Nq) {
            qx[r] = tpq[q * 3]; qy[r] = tpq[q * 3 + 1]; qz[r] = tpq[q * 3 + 2];
        } else {
            qx[r] = 0.0f; qy[r] = 0.0f; qz[r] = 0.0f;
        }
        q2[r] = qx[r] * qx[r] + qy[r] * qy[r] + qz[r] * qz[r];
        b0[r] = 3.4e38f; b1[r] = 3.4e38f; b2[r] = 3.4e38f;
        i0[r] = 0; i1[r] = 0; i2[r] = 0;
    }

    __shared__ float4 pts[KNN_TILE];

    for (int base = x0; base < x1; base += KNN_TILE) {
        int cnt = min(KNN_TILE, x1 - base);
        __syncthreads();
        for (int j = threadIdx.x; j < cnt; j += 256) {
            float px = tpx[(base + j) * 3], py = tpx[(base + j) * 3 + 1], pz = tpx[(base + j) * 3 + 2];
            pts[j] = make_float4(px, py, pz, 0.5f * (px * px + py * py + pz * pz));
        }
        __syncthreads();
#pragma unroll 8
        for (int j = 0; j < cnt; ++j) {
            float4 p = pts[j];
            int id = base + j;
#pragma unroll
            for (int r = 0; r < KNN_Q; ++r) {
                float s = fmaf(-qx[r], p.x, fmaf(-qy[r], p.y, fmaf(-qz[r], p.z, p.w)));
                if (s < b2[r]) {
                    if (s < b1[r]) {
                        b2[r] = b1[r]; i2[r] = i1[r];
                        if (s < b0[r]) { b1[r] = b0[r]; i1[r] = i0[r]; b0[r] = s; i0[r] = id; }
                        else           { b1[r] = s;     i1[r] = id; }
                    } else { b2[r] = s; i2[r] = id; }
                }
            }
        }
    }
#pragma unroll
    for (int r = 0; r < KNN_Q; ++r) {
        int q = q0 + r * 256;
        if (q < Nq) {
            size_t o = ((size_t)blockIdx.y * Nq + q) * 3;
            pd[o + 0] = fmaf(2.0f, b0[r], q2[r]);
            pd[o + 1] = fmaf(2.0f, b1[r], q2[r]);
            pd[o + 2] = fmaf(2.0f, b2[r], q2[r]);
            pi[o + 0] = i0[r]; pi[o + 1] = i1[r]; pi[o + 2] = i2[r];
        }
    }
}

__global__ void k_knn_merge(const float* __restrict__ pd, const int* __restrict__ pi,
                            int Nq, int nchunk,
                            int* __restrict__ oidx, float* __restrict__ ow)
{
    int q = blockIdx.x * 256 + threadIdx.x;
    if (q >= Nq) return;
    size_t o = (size_t)q * 3;
    float b0 = pd[o], b1 = pd[o + 1], b2 = pd[o + 2];
    int   i0 = pi[o], i1 = pi[o + 1], i2 = pi[o + 2];
    for (int c = 1; c < nchunk; ++c) {
        size_t oc = ((size_t)c * Nq + q) * 3;
#pragma unroll 3
        for (int k = 0; k < 3; ++k) {
            float d = pd[oc + k];
            int  id = pi[oc + k];
            if (d < b2) {
                if (d < b1) {
                    b2 = b1; i2 = i1;
                    if (d < b0) { b1 = b0; i1 = i0; b0 = d; i0 = id; }
                    else        { b1 = d;  i1 = id; }
                } else { b2 = d; i2 = id; }
            }
        }
    }
    float w0 = 1.0f / fmaxf(b0, 1e-16f);
    float w1 = 1.0f / fmaxf(b1, 1e-16f);
    float w2 = 1.0f / fmaxf(b2, 1e-16f);
    float s = w0 + w1 + w2;
    oidx[q * 3 + 0] = i0; oidx[q * 3 + 1] = i1; oidx[q * 3 + 2] = i2;
    ow[q * 4 + 0] = w0; ow[q * 4 + 1] = w1; ow[q * 4 + 2] = w2; ow[q * 4 + 3] = s;
}

__global__ void k_interp(const float* __restrict__ x, const int* __restrict__ idx,
                         const float* __restrict__ w, float* __restrict__ y, int Nq) {
    int t = blockIdx.x * 256 + threadIdx.x;
    if (t >= Nq * 128) return;
    int j = t >> 7, c = t & 127;
    int i0 = idx[j * 3], i1 = idx[j * 3 + 1], i2 = idx[j * 3 + 2];
    float w0 = w[j * 4], w1 = w[j * 4 + 1], w2 = w[j * 4 + 2], s = w[j * 4 + 3];
    float num = w0 * x[i0 * 128 + c] + w1 * x[i1 * 128 + c] + w2 * x[i2 * 128 + c];
    y[j * 128 + c] = num / s;
}

// ---------- output conv matmul (OC=5), row-scaled by dinv ----------
__global__ __launch_bounds__(256) void k_matmul5(const float* __restrict__ X, const float* __restrict__ P,
                                                 const float* __restrict__ W, const float* __restrict__ rs,
                                                 float* __restrict__ Y, int N) {
    __shared__ float xs[32][132];
    __shared__ float ws[131 * 5];
    int row0 = blockIdx.x * 32;
    for (int idx = threadIdx.x; idx < 131 * 5; idx += 256) ws[idx] = W[idx];
    for (int idx = threadIdx.x; idx < 32 * 128; idx += 256) {
        int r = idx >> 7, c = idx & 127;
        xs[r][c] = X[(size_t)(row0 + r) * 128 + c];
    }
    for (int idx = threadIdx.x; idx < 32 * 3; idx += 256) {
        int r = idx / 3, c = idx % 3;
        xs[r][128 + c] = P[(row0 + r) * 3 + c];
    }
    __syncthreads();
    int r = threadIdx.x >> 3;
    int c = threadIdx.x & 7;
    if (c < 5) {
        float acc = 0.0f;
        for (int i = 0; i < 131; ++i) acc = fmaf(xs[r][i], ws[i * 5 + c], acc);
        Y[(size_t)(row0 + r) * 5 + c] = acc * rs[row0 + r];
    }
}

extern "C" void kernel_launch(void* const* d_in, const int* in_sizes, int n_in,
                              void* d_out, int out_size, void* d_ws, size_t ws_size,
                              hipStream_t stream) {
    const float* latent = (const float*)d_in[0];
    const float* pos0   = (const float*)d_in[1];
    const float* pos1   = (const float*)d_in[2];
    const float* pos2   = (const float*)d_in[3];
    const float* W_lin  = (const float*)d_in[4];
    const float* b_lin  = (const float*)d_in[5];
    const float* W0 = (const float*)d_in[6];  const float* b0 = (const float*)d_in[7];
    const float* W1 = (const float*)d_in[8];  const float* b1 = (const float*)d_in[9];
    const float* W2 = (const float*)d_in[10]; const float* b2 = (const float*)d_in[11];
    const float* W3 = (const float*)d_in[12]; const float* b3 = (const float*)d_in[13];
    const float* W4 = (const float*)d_in[14]; const float* b4 = (const float*)d_in[15];
    const int* ei0 = (const int*)d_in[16];
    const int* ei1 = (const int*)d_in[17];
    const int* ei2 = (const int*)d_in[18];
    float* out = (float*)d_out;

    const int N0 = in_sizes[1] / 3, N1 = in_sizes[2] / 3, N2 = in_sizes[3] / 3;
    const int E0 = in_sizes[16] / 2, E1 = in_sizes[17] / 2, E2 = in_sizes[18] / 2;
    const int NCHUNK = 8;

    char* wsp = (char*)d_ws;
    auto alloc = [&](size_t bytes) {
        char* p = wsp;
        wsp += (bytes + 255) & ~size_t(255);
        return p;
    };
    float* A      = (float*)alloc((size_t)N2 * 128 * 4);
    float* Bb     = (float*)alloc((size_t)N2 * 128 * 4);
    float* tp0    = (float*)alloc((size_t)N0 * 3 * 4);
    float* tp1    = (float*)alloc((size_t)N1 * 3 * 4);
    float* tp2    = (float*)alloc((size_t)N2 * 3 * 4);
    float* dv     = (float*)alloc((size_t)N2 * 4);
    int*   cnt    = (int*)  alloc((size_t)N2 * 4);
    int*   rowptr = (int*)  alloc(((size_t)N2 + 1) * 4);
    int*   cur    = (int*)  alloc((size_t)N2 * 4);
    int*   bsum   = (int*)  alloc(4096);
    int*   csr    = (int*)  alloc((size_t)E2 * 4);
    int*   kidx   = (int*)  alloc((size_t)N2 * 3 * 4);
    float* kw     = (float*)alloc((size_t)N2 * 4 * 4);
    float* ppd    = (float*)alloc((size_t)NCHUNK * N2 * 3 * 4);
    int*   ppi    = (int*)  alloc((size_t)NCHUNK * N2 * 3 * 4);
    float* xw5    = (float*)alloc((size_t)N2 * 5 * 4);

    auto cdiv = [](int a, int b) { return (a + b - 1) / b; };

    // position transforms
    k_transform<<<cdiv(N0, 256), 256, 0, stream>>>(pos0, tp0, N0);
    k_transform<<<cdiv(N1, 256), 256, 0, stream>>>(pos1, tp1, N1);
    k_transform<<<cdiv(N2, 256), 256, 0, stream>>>(pos2, tp2, N2);

    auto build_graph = [&](const int* ei, int E, int N) {
        const int* cols = ei + E;
        hipMemsetAsync(cnt, 0, (size_t)N * 4, stream);
        k_hist<<<cdiv(E, 256), 256, 0, stream>>>(cols, E, cnt);
        k_dinv<<<cdiv(N, 256), 256, 0, stream>>>(cnt, dv, N);
        int nb = cdiv(N, 1024);
        k_scan1<<<nb, 256, 0, stream>>>(cnt, rowptr, bsum, N);
        k_scan2<<<1, 64, 0, stream>>>(bsum, nb);
        k_scan3<<<cdiv(N, 256), 256, 0, stream>>>(rowptr, cur, bsum, N, E);
        k_scatter<<<cdiv(E, 256), 256, 0, stream>>>(ei, cols, E, cur, csr);
    };

    auto conv128 = [&](const float* x, const float* pos, int N,
                       const float* W, const float* b, float* xws, float* outb) {
        k_matmul128<128, true, false, true><<<cdiv(N, 16), 256, 0, stream>>>(x, pos, W, nullptr, dv, xws, N);
        k_gather128<<<cdiv(N * 128, 256), 256, 0, stream>>>(rowptr, csr, xws, dv, b, outb, N);
    };

    auto knn = [&](const float* tpq, int Nq, const float* tpx, int Nx) {
        int chunkLen = cdiv(Nx, NCHUNK);
        dim3 grid(cdiv(Nq, 256 * KNN_Q), NCHUNK);
        k_knn_part<<<grid, 256, 0, stream>>>(tpq, Nq, tpx, Nx, chunkLen, ppd, ppi);
        k_knn_merge<<<cdiv(Nq, 256), 256, 0, stream>>>(ppd, ppi, Nq, NCHUNK, kidx, kw);
    };

    // x = selu(latent @ W_lin + b_lin)  -> A
    k_matmul128<64, false, true, false><<<cdiv(N0, 16), 256, 0, stream>>>(latent, nullptr, W_lin, b_lin, nullptr, A, N0);

    // level 0: two convs
    build_graph(ei0, E0, N0);
    conv128(A, pos0, N0, W0, b0, Bb, A);
    conv128(A, pos0, N0, W1, b1, Bb, A);

    // pool 0 -> 1
    knn(tp1, N1, tp0, N0);
    k_interp<<<cdiv(N1 * 128, 256), 256, 0, stream>>>(A, kidx, kw, Bb, N1);

    // level 1 conv
    build_graph(ei1, E1, N1);
    conv128(Bb, pos1, N1, W2, b2, A, Bb);

    // pool 1 -> 2
    knn(tp2, N2, tp1, N1);
    k_interp<<<cdiv(N2 * 128, 256), 256, 0, stream>>>(Bb, kidx, kw, A, N2);

    // level 2 conv
    build_graph(ei2, E2, N2);
    conv128(A, pos2, N2, W3, b3, Bb, A);

    // output conv (OC=5) — reuses level-2 CSR/dinv
    k_matmul5<<<cdiv(N2, 32), 256, 0, stream>>>(A, pos2, W4, dv, xw5, N2);
    k_gather5<<<cdiv(N2 * 8, 256), 256, 0, stream>>>(rowptr, csr, xw5, dv, b4, out, N2);
}

// Round 5
// 1706.813 us; speedup vs baseline: 3.7664x; 1.0053x over previous
//
#include <hip/hip_runtime.h>
#include <math.h>

#define TAN30f 0.57735026918962576f
#define SELU_SCALE 1.0507009873554805f
#define SELU_ALPHA 1.6732632423543772f

__device__ __forceinline__ float selu_f(float x) {
    return SELU_SCALE * (x > 0.0f ? x : SELU_ALPHA * expm1f(x));
}

// ---------- dense matmul: Y[N,128] = concat(X[N,FIC], P[N,3]?) @ W ----------
template<int FIC, bool HAS_POS, bool BIAS_SELU, bool ROWSCALE>
__global__ __launch_bounds__(256) void k_matmul128(
    const float* __restrict__ X, const float* __restrict__ P,
    const float* __restrict__ W, const float* __restrict__ bias,
    const float* __restrict__ rs,
    float* __restrict__ Y, int N)
{
    constexpr int ICT = FIC + (HAS_POS ? 3 : 0);
    __shared__ float xs[16][ICT + 1];
    int row0 = blockIdx.x * 16;

    for (int idx = threadIdx.x; idx < 16 * FIC; idx += 256) {
        int r = idx / FIC, c = idx % FIC;
        int gr = row0 + r;
        xs[r][c] = (gr < N) ? X[gr * FIC + c] : 0.0f;
    }
    if (HAS_POS) {
        for (int idx = threadIdx.x; idx < 16 * 3; idx += 256) {
            int r = idx / 3, c = idx % 3;
            int gr = row0 + r;
            xs[r][FIC + c] = (gr < N) ? P[gr * 3 + c] : 0.0f;
        }
    }
    __syncthreads();

    int col = threadIdx.x & 127;
    int half = threadIdx.x >> 7;
    float acc[8];
#pragma unroll
    for (int r = 0; r < 8; ++r) acc[r] = 0.0f;

#pragma unroll 4
    for (int i = 0; i < ICT; ++i) {
        float wv = W[i * 128 + col];
#pragma unroll
        for (int r = 0; r < 8; ++r)
            acc[r] = fmaf(xs[half * 8 + r][i], wv, acc[r]);
    }

    float bv = BIAS_SELU ? bias[col] : 0.0f;
#pragma unroll
    for (int r = 0; r < 8; ++r) {
        int gr = row0 + half * 8 + r;
        if (gr < N) {
            float v = acc[r];
            if (BIAS_SELU) v = selu_f(v + bv);
            if (ROWSCALE) v *= rs[gr];
            Y[gr * 128 + col] = v;
        }
    }
}

// ---------- CSR build: histogram -> scan -> scatter ----------
__global__ void k_hist(const int* __restrict__ col, int E, int* __restrict__ cnt) {
    int i = blockIdx.x * 256 + threadIdx.x;
    if (i < E) atomicAdd(&cnt[col[i]], 1);
}

__global__ void k_dinv(const int* __restrict__ cnt, float* __restrict__ dv, int n) {
    int i = blockIdx.x * 256 + threadIdx.x;
    if (i < n) dv[i] = rsqrtf((float)cnt[i] + 1.0f);  // +1 self loop
}

__global__ __launch_bounds__(256) void k_scan1(const int* __restrict__ in, int* __restrict__ out,
                                               int* __restrict__ bsum, int n) {
    __shared__ int s[256];
    int tid = threadIdx.x;
    int base = blockIdx.x * 1024 + tid * 4;
    int a[4];
#pragma unroll
    for (int k = 0; k < 4; ++k) a[k] = (base + k < n) ? in[base + k] : 0;
    int t = a[0] + a[1] + a[2] + a[3];
    s[tid] = t;
    __syncthreads();
    for (int off = 1; off < 256; off <<= 1) {
        int x = (tid >= off) ? s[tid - off] : 0;
        __syncthreads();
        s[tid] += x;
        __syncthreads();
    }
    int run = s[tid] - t;
#pragma unroll
    for (int k = 0; k < 4; ++k) {
        if (base + k < n) out[base + k] = run;
        run += a[k];
    }
    if (tid == 255) bsum[blockIdx.x] = s[255];
}

__global__ void k_scan2(int* __restrict__ bsum, int nb) {
    if (threadIdx.x == 0 && blockIdx.x == 0) {
        int run = 0;
        for (int i = 0; i < nb; ++i) { int v = bsum[i]; bsum[i] = run; run += v; }
    }
}

__global__ void k_scan3(int* __restrict__ rowptr, int* __restrict__ cur,
                        const int* __restrict__ bsum, int n, int E) {
    int i = blockIdx.x * 256 + threadIdx.x;
    if (i < n) {
        int v = rowptr[i] + bsum[i >> 10];
        rowptr[i] = v;
        cur[i] = v;
    }
    if (i == 0) rowptr[n] = E;
}

__global__ void k_scatter(const int* __restrict__ rows, const int* __restrict__ cols, int E,
                          int* __restrict__ cur, int* __restrict__ csr) {
    int e = blockIdx.x * 256 + threadIdx.x;
    if (e < E) {
        int p = atomicAdd(&cur[cols[e]], 1);
        csr[p] = rows[e];
    }
}

// ---------- CSR gather aggregation, fused self-loop + dinv + bias + selu ----------
__global__ __launch_bounds__(256) void k_gather128(
    const int* __restrict__ rowptr, const int* __restrict__ csr,
    const float* __restrict__ xws, const float* __restrict__ dv,
    const float* __restrict__ bias, float* __restrict__ out, int N)
{
    int t = blockIdx.x * 256 + threadIdx.x;
    int node = t >> 7, ch = t & 127;
    if (node >= N) return;
    int s = rowptr[node], e = rowptr[node + 1];
    float acc = xws[(size_t)node * 128 + ch];
    for (int i = s; i < e; ++i) {
        int src = csr[i];
        acc += xws[(size_t)src * 128 + ch];
    }
    float v = acc * dv[node] + bias[ch];
    out[(size_t)node * 128 + ch] = selu_f(v);
}

__global__ __launch_bounds__(256) void k_gather5(
    const int* __restrict__ rowptr, const int* __restrict__ csr,
    const float* __restrict__ xws, const float* __restrict__ dv,
    const float* __restrict__ bias, float* __restrict__ out, int N)
{
    int t = blockIdx.x * 256 + threadIdx.x;
    int node = t >> 3, ch = t & 7;
    if (node >= N || ch >= 5) return;
    int s = rowptr[node], e = rowptr[node + 1];
    float acc = xws[(size_t)node * 5 + ch];
    for (int i = s; i < e; ++i) {
        int src = csr[i];
        acc += xws[(size_t)src * 5 + ch];
    }
    out[(size_t)node * 5 + ch] = acc * dv[node] + bias[ch];
}

// ---------- onera transform; emits float4 {x,y,z, 0.5*|p|^2} ----------
__global__ void k_transform(const float* __restrict__ pos, float4* __restrict__ tp, int n) {
    int i = blockIdx.x * 256 + threadIdx.x;
    if (i < n) {
        float x = pos[i * 3 + 0], y = pos[i * 3 + 1], z = pos[i * 3 + 2];
        float nx = x - TAN30f * y;
        float f = 1.0f + (1.0f / 0.56f - 1.0f) * (y / 1.1963f);
        float X = nx * f, Y = y * f, Z = z * f;
        tp[i] = make_float4(X, Y, Z, 0.5f * (X * X + Y * Y + Z * Z));
    }
}

// ---------- brute-force knn (k=3), chunked; branch-skipped insert chain ----------
// Compare in s-space: s = 0.5*|p|^2 - q.p (monotonic in d per query);
// d = 2*s + |q|^2 recovered at the epilogue.
// Common path is 3 FMA + 1 cmp; insert chain behind the branch (execz-skipped).
#define KNN_TILE 512
__global__ __launch_bounds__(256) void k_knn_part(
    const float4* __restrict__ tpq, int Nq,
    const float4* __restrict__ tpx, int Nx, int chunkLen,
    float* __restrict__ pd, int* __restrict__ pi)
{
    int q = blockIdx.x * 256 + threadIdx.x;
    int x0 = blockIdx.y * chunkLen;
    int x1 = min(x0 + chunkLen, Nx);

    float qx = 0.0f, qy = 0.0f, qz = 0.0f;
    if (q < Nq) {
        float4 t = tpq[q];
        qx = t.x; qy = t.y; qz = t.z;
    }
    float q2 = qx * qx + qy * qy + qz * qz;
    float b0 = 3.4e38f, b1 = 3.4e38f, b2 = 3.4e38f;
    int i0 = 0, i1 = 0, i2 = 0;

    __shared__ float4 pts[KNN_TILE];

    for (int base = x0; base < x1; base += KNN_TILE) {
        int cnt = min(KNN_TILE, x1 - base);
        __syncthreads();
        for (int j = threadIdx.x; j < cnt; j += 256) pts[j] = tpx[base + j];
        __syncthreads();
#pragma unroll 8
        for (int j = 0; j < cnt; ++j) {
            float4 p = pts[j];
            float s = fmaf(-qx, p.x, fmaf(-qy, p.y, fmaf(-qz, p.z, p.w)));
            if (s < b2) {                      // rare: exec-masked insert chain
                int id = base + j;
                if (s < b1) {
                    b2 = b1; i2 = i1;
                    if (s < b0) { b1 = b0; i1 = i0; b0 = s; i0 = id; }
                    else        { b1 = s;  i1 = id; }
                } else { b2 = s; i2 = id; }
            }
        }
    }
    if (q < Nq) {
        size_t o = ((size_t)blockIdx.y * Nq + q) * 3;
        pd[o + 0] = fmaf(2.0f, b0, q2);
        pd[o + 1] = fmaf(2.0f, b1, q2);
        pd[o + 2] = fmaf(2.0f, b2, q2);
        pi[o + 0] = i0; pi[o + 1] = i1; pi[o + 2] = i2;
    }
}

__global__ void k_knn_merge(const float* __restrict__ pd, const int* __restrict__ pi,
                            int Nq, int nchunk,
                            int* __restrict__ oidx, float* __restrict__ ow)
{
    int q = blockIdx.x * 256 + threadIdx.x;
    if (q >= Nq) return;
    size_t o = (size_t)q * 3;
    float b0 = pd[o], b1 = pd[o + 1], b2 = pd[o + 2];
    int   i0 = pi[o], i1 = pi[o + 1], i2 = pi[o + 2];
    for (int c = 1; c < nchunk; ++c) {
        size_t oc = ((size_t)c * Nq + q) * 3;
#pragma unroll 3
        for (int k = 0; k < 3; ++k) {
            float d = pd[oc + k];
            int  id = pi[oc + k];
            if (d < b2) {
                if (d < b1) {
                    b2 = b1; i2 = i1;
                    if (d < b0) { b1 = b0; i1 = i0; b0 = d; i0 = id; }
                    else        { b1 = d;  i1 = id; }
                } else { b2 = d; i2 = id; }
            }
        }
    }
    float w0 = 1.0f / fmaxf(b0, 1e-16f);
    float w1 = 1.0f / fmaxf(b1, 1e-16f);
    float w2 = 1.0f / fmaxf(b2, 1e-16f);
    float s = w0 + w1 + w2;
    oidx[q * 3 + 0] = i0; oidx[q * 3 + 1] = i1; oidx[q * 3 + 2] = i2;
    ow[q * 4 + 0] = w0; ow[q * 4 + 1] = w1; ow[q * 4 + 2] = w2; ow[q * 4 + 3] = s;
}

__global__ void k_interp(const float* __restrict__ x, const int* __restrict__ idx,
                         const float* __restrict__ w, float* __restrict__ y, int Nq) {
    int t = blockIdx.x * 256 + threadIdx.x;
    if (t >= Nq * 128) return;
    int j = t >> 7, c = t & 127;
    int i0 = idx[j * 3], i1 = idx[j * 3 + 1], i2 = idx[j * 3 + 2];
    float w0 = w[j * 4], w1 = w[j * 4 + 1], w2 = w[j * 4 + 2], s = w[j * 4 + 3];
    float num = w0 * x[i0 * 128 + c] + w1 * x[i1 * 128 + c] + w2 * x[i2 * 128 + c];
    y[j * 128 + c] = num / s;
}

// ---------- output conv matmul (OC=5), row-scaled by dinv ----------
__global__ __launch_bounds__(256) void k_matmul5(const float* __restrict__ X, const float* __restrict__ P,
                                                 const float* __restrict__ W, const float* __restrict__ rs,
                                                 float* __restrict__ Y, int N) {
    __shared__ float xs[32][132];
    __shared__ float ws[131 * 5];
    int row0 = blockIdx.x * 32;
    for (int idx = threadIdx.x; idx < 131 * 5; idx += 256) ws[idx] = W[idx];
    for (int idx = threadIdx.x; idx < 32 * 128; idx += 256) {
        int r = idx >> 7, c = idx & 127;
        xs[r][c] = X[(size_t)(row0 + r) * 128 + c];
    }
    for (int idx = threadIdx.x; idx < 32 * 3; idx += 256) {
        int r = idx / 3, c = idx % 3;
        xs[r][128 + c] = P[(row0 + r) * 3 + c];
    }
    __syncthreads();
    int r = threadIdx.x >> 3;
    int c = threadIdx.x & 7;
    if (c < 5) {
        float acc = 0.0f;
        for (int i = 0; i < 131; ++i) acc = fmaf(xs[r][i], ws[i * 5 + c], acc);
        Y[(size_t)(row0 + r) * 5 + c] = acc * rs[row0 + r];
    }
}

extern "C" void kernel_launch(void* const* d_in, const int* in_sizes, int n_in,
                              void* d_out, int out_size, void* d_ws, size_t ws_size,
                              hipStream_t stream) {
    const float* latent = (const float*)d_in[0];
    const float* pos0   = (const float*)d_in[1];
    const float* pos1   = (const float*)d_in[2];
    const float* pos2   = (const float*)d_in[3];
    const float* W_lin  = (const float*)d_in[4];
    const float* b_lin  = (const float*)d_in[5];
    const float* W0 = (const float*)d_in[6];  const float* b0 = (const float*)d_in[7];
    const float* W1 = (const float*)d_in[8];  const float* b1 = (const float*)d_in[9];
    const float* W2 = (const float*)d_in[10]; const float* b2 = (const float*)d_in[11];
    const float* W3 = (const float*)d_in[12]; const float* b3 = (const float*)d_in[13];
    const float* W4 = (const float*)d_in[14]; const float* b4 = (const float*)d_in[15];
    const int* ei0 = (const int*)d_in[16];
    const int* ei1 = (const int*)d_in[17];
    const int* ei2 = (const int*)d_in[18];
    float* out = (float*)d_out;

    const int N0 = in_sizes[1] / 3, N1 = in_sizes[2] / 3, N2 = in_sizes[3] / 3;
    const int E0 = in_sizes[16] / 2, E1 = in_sizes[17] / 2, E2 = in_sizes[18] / 2;
    const int NCHUNK = 4;

    char* wsp = (char*)d_ws;
    auto alloc = [&](size_t bytes) {
        char* p = wsp;
        wsp += (bytes + 255) & ~size_t(255);
        return p;
    };
    float*  A      = (float*)alloc((size_t)N2 * 128 * 4);
    float*  Bb     = (float*)alloc((size_t)N2 * 128 * 4);
    float4* tp0    = (float4*)alloc((size_t)N0 * 16);
    float4* tp1    = (float4*)alloc((size_t)N1 * 16);
    float4* tp2    = (float4*)alloc((size_t)N2 * 16);
    float*  dv     = (float*)alloc((size_t)N2 * 4);
    int*    cnt    = (int*)  alloc((size_t)N2 * 4);
    int*    rowptr = (int*)  alloc(((size_t)N2 + 1) * 4);
    int*    cur    = (int*)  alloc((size_t)N2 * 4);
    int*    bsum   = (int*)  alloc(4096);
    int*    csr    = (int*)  alloc((size_t)E2 * 4);
    int*    kidx   = (int*)  alloc((size_t)N2 * 3 * 4);
    float*  kw     = (float*)alloc((size_t)N2 * 4 * 4);
    float*  ppd    = (float*)alloc((size_t)NCHUNK * N2 * 3 * 4);
    int*    ppi    = (int*)  alloc((size_t)NCHUNK * N2 * 3 * 4);
    float*  xw5    = (float*)alloc((size_t)N2 * 5 * 4);

    auto cdiv = [](int a, int b) { return (a + b - 1) / b; };

    // position transforms (prepacked float4 with 0.5*|p|^2)
    k_transform<<<cdiv(N0, 256), 256, 0, stream>>>(pos0, tp0, N0);
    k_transform<<<cdiv(N1, 256), 256, 0, stream>>>(pos1, tp1, N1);
    k_transform<<<cdiv(N2, 256), 256, 0, stream>>>(pos2, tp2, N2);

    auto build_graph = [&](const int* ei, int E, int N) {
        const int* cols = ei + E;
        hipMemsetAsync(cnt, 0, (size_t)N * 4, stream);
        k_hist<<<cdiv(E, 256), 256, 0, stream>>>(cols, E, cnt);
        k_dinv<<<cdiv(N, 256), 256, 0, stream>>>(cnt, dv, N);
        int nb = cdiv(N, 1024);
        k_scan1<<<nb, 256, 0, stream>>>(cnt, rowptr, bsum, N);
        k_scan2<<<1, 64, 0, stream>>>(bsum, nb);
        k_scan3<<<cdiv(N, 256), 256, 0, stream>>>(rowptr, cur, bsum, N, E);
        k_scatter<<<cdiv(E, 256), 256, 0, stream>>>(ei, cols, E, cur, csr);
    };

    auto conv128 = [&](const float* x, const float* pos, int N,
                       const float* W, const float* b, float* xws, float* outb) {
        k_matmul128<128, true, false, true><<<cdiv(N, 16), 256, 0, stream>>>(x, pos, W, nullptr, dv, xws, N);
        k_gather128<<<cdiv(N * 128, 256), 256, 0, stream>>>(rowptr, csr, xws, dv, b, outb, N);
    };

    auto knn = [&](const float4* tpq, int Nq, const float4* tpx, int Nx) {
        int chunkLen = cdiv(Nx, NCHUNK);
        dim3 grid(cdiv(Nq, 256), NCHUNK);
        k_knn_part<<<grid, 256, 0, stream>>>(tpq, Nq, tpx, Nx, chunkLen, ppd, ppi);
        k_knn_merge<<<cdiv(Nq, 256), 256, 0, stream>>>(ppd, ppi, Nq, NCHUNK, kidx, kw);
    };

    // x = selu(latent @ W_lin + b_lin)  -> A
    k_matmul128<64, false, true, false><<<cdiv(N0, 16), 256, 0, stream>>>(latent, nullptr, W_lin, b_lin, nullptr, A, N0);

    // level 0: two convs
    build_graph(ei0, E0, N0);
    conv128(A, pos0, N0, W0, b0, Bb, A);
    conv128(A, pos0, N0, W1, b1, Bb, A);

    // pool 0 -> 1
    knn(tp1, N1, tp0, N0);
    k_interp<<<cdiv(N1 * 128, 256), 256, 0, stream>>>(A, kidx, kw, Bb, N1);

    // level 1 conv
    build_graph(ei1, E1, N1);
    conv128(Bb, pos1, N1, W2, b2, A, Bb);

    // pool 1 -> 2
    knn(tp2, N2, tp1, N1);
    k_interp<<<cdiv(N2 * 128, 256), 256, 0, stream>>>(Bb, kidx, kw, A, N2);

    // level 2 conv
    build_graph(ei2, E2, N2);
    conv128(A, pos2, N2, W3, b3, Bb, A);

    // output conv (OC=5) — reuses level-2 CSR/dinv
    k_matmul5<<<cdiv(N2, 32), 256, 0, stream>>>(A, pos2, W4, dv, xw5, N2);
    k_gather5<<<cdiv(N2 * 8, 256), 256, 0, stream>>>(rowptr, csr, xw5, dv, b4, out, N2);
}